// Round 1
// baseline (205.728 us; speedup 1.0000x reference)
//
#include <hip/hip_runtime.h>
#include <stdint.h>

// ---------------------------------------------------------------------------
// Fused MHA block: x@Wq^T / x@Wk^T*scale / x@Wv^T -> causal attention with
// torch-style v.reshape(B,S,D,H) head split -> LayerNorm -> @Wo^T.
// B=4 S=1024 E=1024 H=16 D=64. All heavy math in bf16 MFMA, fp32 accum.
// ---------------------------------------------------------------------------

using bf16x8 = __attribute__((ext_vector_type(8))) short;
using f32x4  = __attribute__((ext_vector_type(4))) float;
using u16x8  = __attribute__((ext_vector_type(8))) unsigned short;

#define AS1 __attribute__((address_space(1)))
#define AS3 __attribute__((address_space(3)))

__device__ __forceinline__ void gload16(const void* g, void* l) {
  // async global->LDS, 16B per lane; LDS dest is wave-uniform base + lane*16
  __builtin_amdgcn_global_load_lds((const AS1 uint32_t*)g, (AS3 uint32_t*)l, 16, 0, 0);
}

__device__ __forceinline__ unsigned short f2bf(float f) {  // RNE f32->bf16
  union { float f; uint32_t u; } v; v.f = f;
  uint32_t u = v.u + 0x7fffu + ((v.u >> 16) & 1u);
  return (unsigned short)(u >> 16);
}
__device__ __forceinline__ float bf2f(unsigned short h) {
  union { uint32_t u; float f; } v; v.u = ((uint32_t)h) << 16;
  return v.f;
}

// ---------------- fp32 -> bf16 convert (optionally scaled) ------------------
__global__ void cvt_bf16(const float* __restrict__ in, unsigned short* __restrict__ out,
                         int n4, float scale) {
  int i = blockIdx.x * blockDim.x + threadIdx.x;
  if (i >= n4) return;
  float4 v = reinterpret_cast<const float4*>(in)[i];
  ushort4 o;
  o.x = f2bf(v.x * scale);
  o.y = f2bf(v.y * scale);
  o.z = f2bf(v.z * scale);
  o.w = f2bf(v.w * scale);
  reinterpret_cast<ushort4*>(out)[i] = o;
}

// ---------------- GEMM (A[M,K] * B[N,K]^T), m97 structure -------------------
// 128x128 tile, BK=32, 4 waves (2x2), each wave 64x64 via 4x4 16x16x32 MFMAs.
template<int OUTF32>
__global__ __launch_bounds__(256, 2) void gemm_bt(const unsigned short* __restrict__ A,
                                                  const unsigned short* __restrict__ B,
                                                  void* __restrict__ Cv,
                                                  int M, int N, int K) {
  (void)M;
  __shared__ __align__(16) unsigned short lA[128 * 32];
  __shared__ __align__(16) unsigned short lB[128 * 32];
  const int tn_cnt = N >> 7;
  const int nwg = gridDim.x;
  int bid = (int)blockIdx.x;
  int bid2 = (bid & 7) * (nwg >> 3) + (bid >> 3);   // XCD swizzle (nwg%8==0)
  int tm = bid2 / tn_cnt, tn = bid2 % tn_cnt;
  int t = (int)threadIdx.x;
  int w = t >> 6, lane = t & 63, lr = lane & 15, hi = lane >> 4;
  int wr = w >> 1, wc = w & 1;
  int srow = t >> 2, scol = (t & 3) << 3;           // 16B chunk -> (row, col8)
  const unsigned short* a0 = A + (size_t)(tm * 128 + srow) * K + scol;
  const unsigned short* a1 = a0 + (size_t)64 * K;
  const unsigned short* b0 = B + (size_t)(tn * 128 + srow) * K + scol;
  const unsigned short* b1 = b0 + (size_t)64 * K;
  char* dA0 = (char*)lA + w * 1024;
  char* dA1 = (char*)lA + 4096 + w * 1024;
  char* dB0 = (char*)lB + w * 1024;
  char* dB1 = (char*)lB + 4096 + w * 1024;
  f32x4 acc[4][4] = {};
  for (int k0 = 0; k0 < K; k0 += 32) {
    __syncthreads();
    gload16(a0 + k0, dA0);
    gload16(a1 + k0, dA1);
    gload16(b0 + k0, dB0);
    gload16(b1 + k0, dB1);
    __syncthreads();
    bf16x8 af[4], bfr[4];
#pragma unroll
    for (int mi = 0; mi < 4; ++mi)
      af[mi] = *reinterpret_cast<const bf16x8*>(&lA[(wr * 64 + mi * 16 + lr) * 32 + hi * 8]);
#pragma unroll
    for (int ni = 0; ni < 4; ++ni)
      bfr[ni] = *reinterpret_cast<const bf16x8*>(&lB[(wc * 64 + ni * 16 + lr) * 32 + hi * 8]);
#pragma unroll
    for (int mi = 0; mi < 4; ++mi)
#pragma unroll
      for (int ni = 0; ni < 4; ++ni)
        acc[mi][ni] = __builtin_amdgcn_mfma_f32_16x16x32_bf16(af[mi], bfr[ni], acc[mi][ni], 0, 0, 0);
  }
  // C/D layout: col = lane&15, row = (lane>>4)*4 + reg   [m89-verified]
#pragma unroll
  for (int mi = 0; mi < 4; ++mi) {
#pragma unroll
    for (int r = 0; r < 4; ++r) {
      size_t row = (size_t)(tm * 128 + wr * 64 + mi * 16 + hi * 4 + r);
#pragma unroll
      for (int ni = 0; ni < 4; ++ni) {
        int col = tn * 128 + wc * 64 + ni * 16 + lr;
        float v = acc[mi][ni][r];
        if (OUTF32) reinterpret_cast<float*>(Cv)[row * N + col] = v;
        else        reinterpret_cast<unsigned short*>(Cv)[row * N + col] = f2bf(v);
      }
    }
  }
}

// ---------------- V repack: QKV v-part [s][d*16+h] -> VhT [b,h][d][s] -------
__global__ __launch_bounds__(256) void vrepack(const unsigned short* __restrict__ QKV,
                                               unsigned short* __restrict__ VhT) {
  __shared__ __align__(16) unsigned short lT[64 * 72];   // +8 pad vs 64
  int st = (int)blockIdx.x;   // s-tile (16)
  int ct = (int)blockIdx.y;   // c-tile (16)
  int b  = (int)blockIdx.z;   // batch (4)
  int t = (int)threadIdx.x;
#pragma unroll
  for (int i = 0; i < 2; ++i) {
    int c = i * 256 + t;
    int row = c >> 3, ch = c & 7;
    u16x8 v = *reinterpret_cast<const u16x8*>(
        QKV + (size_t)(b * 1024 + st * 64 + row) * 3072 + 2048 + ct * 64 + ch * 8);
    *reinterpret_cast<u16x8*>(&lT[row * 72 + ch * 8]) = v;
  }
  __syncthreads();
#pragma unroll
  for (int i = 0; i < 2; ++i) {
    int c2 = i * 256 + t;
    int cl = c2 >> 3, ch = c2 & 7;
    int h = cl & 15;
    int d = ct * 4 + (cl >> 4);
    u16x8 v;
#pragma unroll
    for (int j = 0; j < 8; ++j) v[j] = lT[(ch * 8 + j) * 72 + cl];
    *reinterpret_cast<u16x8*>(
        VhT + (size_t)((b * 16 + h) * 64 + d) * 1024 + st * 64 + ch * 8) = v;
  }
}

// ---------------- flash attention (causal), bf16 MFMA -----------------------
// grid 512 = (b,h) x 8 q-tiles (qt heavy-first). block = 4 waves x 32 q-rows.
// All LDS tiles XOR-swizzled: byte ^= (row&7)<<4; global_load_lds sources are
// pre-swizzled with the same involution (rule #21).
__global__ __launch_bounds__(256, 2) void attn_fwd(const unsigned short* __restrict__ QKV,
                                                   const unsigned short* __restrict__ VhT,
                                                   unsigned short* __restrict__ Out) {
  __shared__ __align__(16) unsigned short lQ[128 * 64];
  __shared__ __align__(16) unsigned short lK[64 * 64];
  __shared__ __align__(16) unsigned short lV[64 * 64];
  __shared__ __align__(16) unsigned short lP[4][32 * 64];
  int bid = (int)blockIdx.x;
  int qt = 7 - (bid & 7);
  int bh = bid >> 3;
  int b = bh >> 4, h = bh & 15;
  int t = (int)threadIdx.x;
  int w = t >> 6, lane = t & 63, lr = lane & 15, hi = lane >> 4;
  (void)lane;
  // ---- stage Q tile [128][64] ----
#pragma unroll
  for (int i = 0; i < 4; ++i) {
    int c = i * 256 + t;
    int row = c >> 3, slot = c & 7;
    gload16(QKV + (size_t)(b * 1024 + qt * 128 + row) * 3072 + h * 64 + ((slot ^ (row & 7)) << 3),
            (char*)lQ + i * 4096 + w * 1024);
  }
  __syncthreads();
  // ---- Q fragments to registers (A-operand: row=lane&15, k=(lane>>4)*8+j) --
  bf16x8 qfr[2][2];
#pragma unroll
  for (int qf = 0; qf < 2; ++qf)
#pragma unroll
    for (int kc = 0; kc < 2; ++kc) {
      int row = w * 32 + qf * 16 + lr;
      int slot = (kc * 4 + hi) ^ (row & 7);
      qfr[qf][kc] = *reinterpret_cast<const bf16x8*>((const char*)lQ + row * 128 + slot * 16);
    }
  int qbase = qt * 128 + w * 32;
  f32x4 o[2][4] = {};
  float mrun[2][4], lpart[2][4];
#pragma unroll
  for (int qf = 0; qf < 2; ++qf)
#pragma unroll
    for (int r = 0; r < 4; ++r) { mrun[qf][r] = -1e30f; lpart[qf][r] = 0.f; }
  int nkb = 2 * qt + 2;
  for (int kb = 0; kb < nkb; ++kb) {
    __syncthreads();
#pragma unroll
    for (int i = 0; i < 2; ++i) {
      int c = i * 256 + t;
      int row = c >> 3, slot = c & 7;
      gload16(QKV + (size_t)(b * 1024 + kb * 64 + row) * 3072 + 1024 + h * 64 + ((slot ^ (row & 7)) << 3),
              (char*)lK + i * 4096 + w * 1024);
    }
#pragma unroll
    for (int i = 0; i < 2; ++i) {
      int c = i * 256 + t;
      int row = c >> 3, slot = c & 7;
      gload16(VhT + (size_t)(bh * 64 + row) * 1024 + kb * 64 + ((slot ^ (row & 7)) << 3),
              (char*)lV + i * 4096 + w * 1024);
    }
    __syncthreads();
    if (kb * 64 > qbase + 31) continue;   // wave fully masked (barriers stay aligned)
    // ---- S = Q K^T ----
    bf16x8 kfr[4][2];
#pragma unroll
    for (int nf = 0; nf < 4; ++nf)
#pragma unroll
      for (int kc = 0; kc < 2; ++kc) {
        int row = nf * 16 + lr;
        int slot = (kc * 4 + hi) ^ (row & 7);
        kfr[nf][kc] = *reinterpret_cast<const bf16x8*>((const char*)lK + row * 128 + slot * 16);
      }
    f32x4 s[2][4] = {};
#pragma unroll
    for (int qf = 0; qf < 2; ++qf)
#pragma unroll
      for (int nf = 0; nf < 4; ++nf)
#pragma unroll
        for (int kc = 0; kc < 2; ++kc)
          s[qf][nf] = __builtin_amdgcn_mfma_f32_16x16x32_bf16(qfr[qf][kc], kfr[nf][kc], s[qf][nf], 0, 0, 0);
    // ---- causal mask (diagonal blocks only) ----
    if (kb * 64 + 63 > qbase) {
#pragma unroll
      for (int qf = 0; qf < 2; ++qf)
#pragma unroll
        for (int nf = 0; nf < 4; ++nf)
#pragma unroll
          for (int r = 0; r < 4; ++r) {
            int q = qbase + qf * 16 + hi * 4 + r;
            int kv = kb * 64 + nf * 16 + lr;
            if (kv > q) s[qf][nf][r] = -1e30f;
          }
    }
    // ---- online softmax ----
#pragma unroll
    for (int qf = 0; qf < 2; ++qf) {
      float rm[4];
#pragma unroll
      for (int r = 0; r < 4; ++r)
        rm[r] = fmaxf(fmaxf(s[qf][0][r], s[qf][1][r]), fmaxf(s[qf][2][r], s[qf][3][r]));
#pragma unroll
      for (int r = 0; r < 4; ++r) {
        rm[r] = fmaxf(rm[r], __shfl_xor(rm[r], 1));
        rm[r] = fmaxf(rm[r], __shfl_xor(rm[r], 2));
        rm[r] = fmaxf(rm[r], __shfl_xor(rm[r], 4));
        rm[r] = fmaxf(rm[r], __shfl_xor(rm[r], 8));
      }
#pragma unroll
      for (int r = 0; r < 4; ++r) {
        float mn = fmaxf(mrun[qf][r], rm[r]);
        float al = __expf(mrun[qf][r] - mn);
        mrun[qf][r] = mn;
        float ps = 0.f;
#pragma unroll
        for (int nf = 0; nf < 4; ++nf) {
          float p = __expf(s[qf][nf][r] - mn);
          s[qf][nf][r] = p;
          ps += p;
        }
        lpart[qf][r] = lpart[qf][r] * al + ps;
#pragma unroll
        for (int df = 0; df < 4; ++df) o[qf][df][r] *= al;
      }
    }
    // ---- P (bf16) -> wave-private LDS slab, swizzled ----
    char* pb = (char*)lP[w];
#pragma unroll
    for (int qf = 0; qf < 2; ++qf)
#pragma unroll
      for (int nf = 0; nf < 4; ++nf)
#pragma unroll
        for (int r = 0; r < 4; ++r) {
          int rp = qf * 16 + hi * 4 + r;
          int col = nf * 16 + lr;
          int slot = (col >> 3) ^ (rp & 7);
          *reinterpret_cast<unsigned short*>(pb + rp * 128 + slot * 16 + (col & 7) * 2) =
              f2bf(s[qf][nf][r]);
        }
    asm volatile("s_waitcnt lgkmcnt(0)" ::: "memory");
    __builtin_amdgcn_sched_barrier(0);
    // ---- O += P V ----
    bf16x8 pfr[2][2], vfr[4][2];
#pragma unroll
    for (int qf = 0; qf < 2; ++qf)
#pragma unroll
      for (int kc = 0; kc < 2; ++kc) {
        int row = qf * 16 + lr;
        int slot = (kc * 4 + hi) ^ (row & 7);
        pfr[qf][kc] = *reinterpret_cast<const bf16x8*>(pb + row * 128 + slot * 16);
      }
#pragma unroll
    for (int df = 0; df < 4; ++df)
#pragma unroll
      for (int kc = 0; kc < 2; ++kc) {
        int row = df * 16 + lr;
        int slot = (kc * 4 + hi) ^ (row & 7);
        vfr[df][kc] = *reinterpret_cast<const bf16x8*>((const char*)lV + row * 128 + slot * 16);
      }
#pragma unroll
    for (int qf = 0; qf < 2; ++qf)
#pragma unroll
      for (int df = 0; df < 4; ++df)
#pragma unroll
        for (int kc = 0; kc < 2; ++kc)
          o[qf][df] = __builtin_amdgcn_mfma_f32_16x16x32_bf16(pfr[qf][kc], vfr[df][kc], o[qf][df], 0, 0, 0);
  }
  // ---- finalize: full row-sum, normalize, store bf16 [b,t][h*64+d] ----
#pragma unroll
  for (int qf = 0; qf < 2; ++qf)
#pragma unroll
    for (int r = 0; r < 4; ++r) {
      float l = lpart[qf][r];
      l += __shfl_xor(l, 1);
      l += __shfl_xor(l, 2);
      l += __shfl_xor(l, 4);
      l += __shfl_xor(l, 8);
      float inv = 1.0f / l;
      int qrow = qbase + qf * 16 + hi * 4 + r;
#pragma unroll
      for (int df = 0; df < 4; ++df)
        Out[(size_t)(b * 1024 + qrow) * 1024 + h * 64 + df * 16 + lr] = f2bf(o[qf][df][r] * inv);
    }
}

// ---------------- LayerNorm over E=1024, wave per row -----------------------
__global__ __launch_bounds__(256) void lnorm(const unsigned short* __restrict__ X,
                                             unsigned short* __restrict__ Y,
                                             const float* __restrict__ gamma,
                                             const float* __restrict__ beta) {
  int rowi = (int)blockIdx.x * 4 + ((int)threadIdx.x >> 6);
  int lane = (int)threadIdx.x & 63;
  const unsigned short* row = X + (size_t)rowi * 1024;
  u16x8 v0 = reinterpret_cast<const u16x8*>(row)[lane];
  u16x8 v1 = reinterpret_cast<const u16x8*>(row)[lane + 64];
  float f0[8], f1[8];
  float s = 0.f, sq = 0.f;
#pragma unroll
  for (int j = 0; j < 8; ++j) {
    f0[j] = bf2f(v0[j]); f1[j] = bf2f(v1[j]);
    s  += f0[j] + f1[j];
    sq += f0[j] * f0[j] + f1[j] * f1[j];
  }
#pragma unroll
  for (int m = 1; m <= 32; m <<= 1) { s += __shfl_xor(s, m); sq += __shfl_xor(sq, m); }
  float mean = s * (1.0f / 1024.0f);
  float var  = sq * (1.0f / 1024.0f) - mean * mean;
  float rstd = rsqrtf(var + 1e-5f);
  int c0 = lane * 8, c1 = 512 + lane * 8;
  u16x8 o0, o1;
#pragma unroll
  for (int j = 0; j < 8; ++j) {
    o0[j] = f2bf((f0[j] - mean) * rstd * gamma[c0 + j] + beta[c0 + j]);
    o1[j] = f2bf((f1[j] - mean) * rstd * gamma[c1 + j] + beta[c1 + j]);
  }
  reinterpret_cast<u16x8*>(Y + (size_t)rowi * 1024)[lane]      = o0;
  reinterpret_cast<u16x8*>(Y + (size_t)rowi * 1024)[lane + 64] = o1;
}

// ---------------------------------------------------------------------------
extern "C" void kernel_launch(void* const* d_in, const int* in_sizes, int n_in,
                              void* d_out, int out_size, void* d_ws, size_t ws_size,
                              hipStream_t stream) {
  (void)in_sizes; (void)n_in; (void)out_size; (void)ws_size;
  const float* x     = (const float*)d_in[0];
  const float* Wq    = (const float*)d_in[1];
  const float* Wk    = (const float*)d_in[2];
  const float* Wv    = (const float*)d_in[3];
  const float* Wo    = (const float*)d_in[4];
  const float* gamma = (const float*)d_in[5];
  const float* beta  = (const float*)d_in[6];
  char* ws = (char*)d_ws;
  unsigned short* xb   = (unsigned short*)(ws);                    //  8MB [0,8)
  unsigned short* wcat = (unsigned short*)(ws + (8u  << 20));      //  6MB [8,14)
  unsigned short* wob  = (unsigned short*)(ws + (14u << 20));      //  2MB [14,16)
  unsigned short* qkv  = (unsigned short*)(ws + (16u << 20));      // 24MB [16,40)
  unsigned short* vht  = (unsigned short*)(ws + (40u << 20));      //  8MB [40,48)
  unsigned short* att  = (unsigned short*)(ws + (48u << 20));      //  8MB [48,56)
  unsigned short* lnb  = (unsigned short*)(ws + (56u << 20));      //  8MB [56,64)

  // converts (scale 1/sqrt(64)=0.125 folded into Wk)
  cvt_bf16<<<4096, 256, 0, stream>>>(x,  xb,              1048576, 1.0f);
  cvt_bf16<<<1024, 256, 0, stream>>>(Wq, wcat,             262144, 1.0f);
  cvt_bf16<<<1024, 256, 0, stream>>>(Wk, wcat + 1048576,   262144, 0.125f);
  cvt_bf16<<<1024, 256, 0, stream>>>(Wv, wcat + 2097152,   262144, 1.0f);
  cvt_bf16<<<1024, 256, 0, stream>>>(Wo, wob,              262144, 1.0f);
  // QKV projection: [4096,1024] x [3072,1024]^T -> bf16 [4096,3072]
  gemm_bt<0><<<768, 256, 0, stream>>>(xb, wcat, qkv, 4096, 3072, 1024);
  // V head-transpose repack
  vrepack<<<dim3(16, 16, 4), 256, 0, stream>>>(qkv, vht);
  // causal flash attention
  attn_fwd<<<512, 256, 0, stream>>>(qkv, vht, att);
  // LayerNorm
  lnorm<<<1024, 256, 0, stream>>>(att, lnb, gamma, beta);
  // output projection -> fp32 d_out
  gemm_bt<1><<<256, 256, 0, stream>>>(lnb, wob, (void*)d_out, 4096, 1024, 1024);
}

// Round 5
// 190.236 us; speedup vs baseline: 1.0814x; 1.0814x over previous
//
#include <hip/hip_runtime.h>
#include <stdint.h>

// ---------------------------------------------------------------------------
// Fused MHA block: x@Wq^T / x@Wk^T*scale / x@Wv^T -> causal attention with
// torch-style v.reshape(B,S,D,H) head split -> LayerNorm -> @Wo^T.
// B=4 S=1024 E=1024 H=16 D=64. All heavy math in bf16 MFMA, fp32 accum.
// ---------------------------------------------------------------------------

using bf16x8 = __attribute__((ext_vector_type(8))) short;
using f32x4  = __attribute__((ext_vector_type(4))) float;
using u16x8  = __attribute__((ext_vector_type(8))) unsigned short;

#define AS1 __attribute__((address_space(1)))
#define AS3 __attribute__((address_space(3)))

__device__ __forceinline__ void gload16(const void* g, void* l) {
  // async global->LDS, 16B per lane; LDS dest is wave-uniform base + lane*16
  __builtin_amdgcn_global_load_lds((const AS1 uint32_t*)g, (AS3 uint32_t*)l, 16, 0, 0);
}

__device__ __forceinline__ unsigned short f2bf(float f) {  // RNE f32->bf16
  union { float f; uint32_t u; } v; v.f = f;
  uint32_t u = v.u + 0x7fffu + ((v.u >> 16) & 1u);
  return (unsigned short)(u >> 16);
}
__device__ __forceinline__ float bf2f(unsigned short h) {
  union { uint32_t u; float f; } v; v.u = ((uint32_t)h) << 16;
  return v.f;
}

// ---------------- fused fp32 -> bf16 converts (one launch) ------------------
// regions (float4 units): x 1048576 (!) | Wq 262144 | Wk 262144 (x0.125)
//                         | Wv 262144 | Wo 262144
// x is [4,1024,1024] f32 = 1048576 float4 — R2-R4 bug was sizing it 262144.
__global__ __launch_bounds__(256) void cvt_all(const float* __restrict__ x,
                                               const float* __restrict__ Wq,
                                               const float* __restrict__ Wk,
                                               const float* __restrict__ Wv,
                                               const float* __restrict__ Wo,
                                               unsigned short* __restrict__ xb,
                                               unsigned short* __restrict__ wcat,
                                               unsigned short* __restrict__ wob) {
  int i = (int)blockIdx.x * 256 + (int)threadIdx.x;   // 2097152 total
  const float* src; unsigned short* dst; int off; float scale = 1.0f;
  if (i < 1048576)      { src = x;  dst = xb;             off = i; }
  else if (i < 1310720) { src = Wq; dst = wcat;           off = i - 1048576; }
  else if (i < 1572864) { src = Wk; dst = wcat + 1048576; off = i - 1310720; scale = 0.125f; }
  else if (i < 1835008) { src = Wv; dst = wcat + 2097152; off = i - 1572864; }
  else                  { src = Wo; dst = wob;            off = i - 1835008; }
  float4 v = reinterpret_cast<const float4*>(src)[off];
  ushort4 o;
  o.x = f2bf(v.x * scale);
  o.y = f2bf(v.y * scale);
  o.z = f2bf(v.z * scale);
  o.w = f2bf(v.w * scale);
  reinterpret_cast<ushort4*>(dst)[off] = o;
}

// ---------------- GEMM (A[M,K] * B[N,K]^T), m97 structure -------------------
// 128x128 tile, BK=32, 4 waves (2x2), each wave 64x64 via 4x4 16x16x32 MFMAs.
template<int OUTF32>
__global__ __launch_bounds__(256, 2) void gemm_bt(const unsigned short* __restrict__ A,
                                                  const unsigned short* __restrict__ B,
                                                  void* __restrict__ Cv,
                                                  int M, int N, int K) {
  (void)M;
  __shared__ __align__(16) unsigned short lA[128 * 32];
  __shared__ __align__(16) unsigned short lB[128 * 32];
  const int tn_cnt = N >> 7;
  const int nwg = gridDim.x;
  int bid = (int)blockIdx.x;
  int bid2 = (bid & 7) * (nwg >> 3) + (bid >> 3);   // XCD swizzle (nwg%8==0)
  int tm = bid2 / tn_cnt, tn = bid2 % tn_cnt;
  int t = (int)threadIdx.x;
  int w = t >> 6, lane = t & 63, lr = lane & 15, hi = lane >> 4;
  int wr = w >> 1, wc = w & 1;
  int srow = t >> 2, scol = (t & 3) << 3;           // 16B chunk -> (row, col8)
  const unsigned short* a0 = A + (size_t)(tm * 128 + srow) * K + scol;
  const unsigned short* a1 = a0 + (size_t)64 * K;
  const unsigned short* b0 = B + (size_t)(tn * 128 + srow) * K + scol;
  const unsigned short* b1 = b0 + (size_t)64 * K;
  char* dA0 = (char*)lA + w * 1024;
  char* dA1 = (char*)lA + 4096 + w * 1024;
  char* dB0 = (char*)lB + w * 1024;
  char* dB1 = (char*)lB + 4096 + w * 1024;
  f32x4 acc[4][4] = {};
  for (int k0 = 0; k0 < K; k0 += 32) {
    __syncthreads();
    gload16(a0 + k0, dA0);
    gload16(a1 + k0, dA1);
    gload16(b0 + k0, dB0);
    gload16(b1 + k0, dB1);
    __syncthreads();
    bf16x8 af[4], bfr[4];
#pragma unroll
    for (int mi = 0; mi < 4; ++mi)
      af[mi] = *reinterpret_cast<const bf16x8*>(&lA[(wr * 64 + mi * 16 + lr) * 32 + hi * 8]);
#pragma unroll
    for (int ni = 0; ni < 4; ++ni)
      bfr[ni] = *reinterpret_cast<const bf16x8*>(&lB[(wc * 64 + ni * 16 + lr) * 32 + hi * 8]);
#pragma unroll
    for (int mi = 0; mi < 4; ++mi)
#pragma unroll
      for (int ni = 0; ni < 4; ++ni)
        acc[mi][ni] = __builtin_amdgcn_mfma_f32_16x16x32_bf16(af[mi], bfr[ni], acc[mi][ni], 0, 0, 0);
  }
  // C/D layout: col = lane&15, row = (lane>>4)*4 + reg   [m89-verified]
#pragma unroll
  for (int mi = 0; mi < 4; ++mi) {
#pragma unroll
    for (int r = 0; r < 4; ++r) {
      size_t row = (size_t)(tm * 128 + wr * 64 + mi * 16 + hi * 4 + r);
#pragma unroll
      for (int ni = 0; ni < 4; ++ni) {
        int col = tn * 128 + wc * 64 + ni * 16 + lr;
        float v = acc[mi][ni][r];
        if (OUTF32) reinterpret_cast<float*>(Cv)[row * N + col] = v;
        else        reinterpret_cast<unsigned short*>(Cv)[row * N + col] = f2bf(v);
      }
    }
  }
}

// ---------------- V repack: QKV v-part [s][d*16+h] -> VhT [b,h][d][s] -------
__global__ __launch_bounds__(256) void vrepack(const unsigned short* __restrict__ QKV,
                                               unsigned short* __restrict__ VhT) {
  __shared__ __align__(16) unsigned short lT[64 * 72];   // +8 pad vs 64
  int st = (int)blockIdx.x;   // s-tile (16)
  int ct = (int)blockIdx.y;   // c-tile (16)
  int b  = (int)blockIdx.z;   // batch (4)
  int t = (int)threadIdx.x;
#pragma unroll
  for (int i = 0; i < 2; ++i) {
    int c = i * 256 + t;
    int row = c >> 3, ch = c & 7;
    u16x8 v = *reinterpret_cast<const u16x8*>(
        QKV + (size_t)(b * 1024 + st * 64 + row) * 3072 + 2048 + ct * 64 + ch * 8);
    *reinterpret_cast<u16x8*>(&lT[row * 72 + ch * 8]) = v;
  }
  __syncthreads();
#pragma unroll
  for (int i = 0; i < 2; ++i) {
    int c2 = i * 256 + t;
    int cl = c2 >> 3, ch = c2 & 7;
    int h = cl & 15;
    int d = ct * 4 + (cl >> 4);
    u16x8 v;
#pragma unroll
    for (int j = 0; j < 8; ++j) v[j] = lT[(ch * 8 + j) * 72 + cl];
    *reinterpret_cast<u16x8*>(
        VhT + (size_t)((b * 16 + h) * 64 + d) * 1024 + st * 64 + ch * 8) = v;
  }
}

// ---------------- flash attention (causal), bf16 MFMA -----------------------
// grid 512: bid -> (bh, qt) with qt = (bid>>8)? (bid&3) : 7-(bid&3) so blocks
// bid and bid+256 have complementary work (load balance across CUs).
// K/V double-buffered in LDS; next tile prefetched at loop top, one
// __syncthreads() per iteration.
// All LDS tiles XOR-swizzled: byte ^= (row&7)<<4; global_load_lds sources are
// pre-swizzled with the same involution (rule #21).
__global__ __launch_bounds__(256, 2) void attn_fwd(const unsigned short* __restrict__ QKV,
                                                   const unsigned short* __restrict__ VhT,
                                                   unsigned short* __restrict__ Out) {
  __shared__ __align__(16) unsigned short lQ[128 * 64];
  __shared__ __align__(16) unsigned short lK[2][64 * 64];
  __shared__ __align__(16) unsigned short lV[2][64 * 64];
  __shared__ __align__(16) unsigned short lP[4][32 * 64];
  int bid = (int)blockIdx.x;
  int half = bid >> 8, idx = bid & 255;
  int bh = idx >> 2, jj = idx & 3;
  int qt = half ? jj : 7 - jj;
  int b = bh >> 4, h = bh & 15;
  int t = (int)threadIdx.x;
  int w = t >> 6, lane = t & 63, lr = lane & 15, hi = lane >> 4;
  (void)lane;

  auto stageKV = [&](int kb, int buf) {
#pragma unroll
    for (int i = 0; i < 2; ++i) {
      int c = i * 256 + t;
      int row = c >> 3, slot = c & 7;
      gload16(QKV + (size_t)(b * 1024 + kb * 64 + row) * 3072 + 1024 + h * 64 + ((slot ^ (row & 7)) << 3),
              (char*)lK + buf * 8192 + i * 4096 + w * 1024);
    }
#pragma unroll
    for (int i = 0; i < 2; ++i) {
      int c = i * 256 + t;
      int row = c >> 3, slot = c & 7;
      gload16(VhT + (size_t)(bh * 64 + row) * 1024 + kb * 64 + ((slot ^ (row & 7)) << 3),
              (char*)lV + buf * 8192 + i * 4096 + w * 1024);
    }
  };

  // ---- stage Q tile [128][64] + first K/V tile ----
#pragma unroll
  for (int i = 0; i < 4; ++i) {
    int c = i * 256 + t;
    int row = c >> 3, slot = c & 7;
    gload16(QKV + (size_t)(b * 1024 + qt * 128 + row) * 3072 + h * 64 + ((slot ^ (row & 7)) << 3),
            (char*)lQ + i * 4096 + w * 1024);
  }
  stageKV(0, 0);
  __syncthreads();

  // ---- Q fragments to registers (A-operand: row=lane&15, k=(lane>>4)*8+j) --
  bf16x8 qfr[2][2];
#pragma unroll
  for (int qf = 0; qf < 2; ++qf)
#pragma unroll
    for (int kc = 0; kc < 2; ++kc) {
      int row = w * 32 + qf * 16 + lr;
      int slot = (kc * 4 + hi) ^ (row & 7);
      qfr[qf][kc] = *reinterpret_cast<const bf16x8*>((const char*)lQ + row * 128 + slot * 16);
    }
  int qbase = qt * 128 + w * 32;
  f32x4 o[2][4] = {};
  float mrun[2][4], lpart[2][4];
#pragma unroll
  for (int qf = 0; qf < 2; ++qf)
#pragma unroll
    for (int r = 0; r < 4; ++r) { mrun[qf][r] = -1e30f; lpart[qf][r] = 0.f; }

  int nkb = 2 * qt + 2;
  for (int kb = 0; kb < nkb; ++kb) {
    int cur = kb & 1;
    // ---- prefetch next K/V tile into the other buffer ----
    if (kb + 1 < nkb) stageKV(kb + 1, cur ^ 1);
    if (kb * 64 <= qbase + 31) {   // wave has unmasked work
      const char* kbuf = (const char*)lK + cur * 8192;
      const char* vbuf = (const char*)lV + cur * 8192;
      // ---- S = Q K^T ----
      bf16x8 kfr[4][2];
#pragma unroll
      for (int nf = 0; nf < 4; ++nf)
#pragma unroll
        for (int kc = 0; kc < 2; ++kc) {
          int row = nf * 16 + lr;
          int slot = (kc * 4 + hi) ^ (row & 7);
          kfr[nf][kc] = *reinterpret_cast<const bf16x8*>(kbuf + row * 128 + slot * 16);
        }
      f32x4 s[2][4] = {};
#pragma unroll
      for (int qf = 0; qf < 2; ++qf)
#pragma unroll
        for (int nf = 0; nf < 4; ++nf)
#pragma unroll
          for (int kc = 0; kc < 2; ++kc)
            s[qf][nf] = __builtin_amdgcn_mfma_f32_16x16x32_bf16(qfr[qf][kc], kfr[nf][kc], s[qf][nf], 0, 0, 0);
      // ---- V fragments issued early (overlap with softmax VALU) ----
      bf16x8 vfr[4][2];
#pragma unroll
      for (int df = 0; df < 4; ++df)
#pragma unroll
        for (int kc = 0; kc < 2; ++kc) {
          int row = df * 16 + lr;
          int slot = (kc * 4 + hi) ^ (row & 7);
          vfr[df][kc] = *reinterpret_cast<const bf16x8*>(vbuf + row * 128 + slot * 16);
        }
      // ---- causal mask (diagonal blocks only) ----
      if (kb * 64 + 63 > qbase) {
#pragma unroll
        for (int qf = 0; qf < 2; ++qf)
#pragma unroll
          for (int nf = 0; nf < 4; ++nf)
#pragma unroll
            for (int r = 0; r < 4; ++r) {
              int q = qbase + qf * 16 + hi * 4 + r;
              int kv = kb * 64 + nf * 16 + lr;
              if (kv > q) s[qf][nf][r] = -1e30f;
            }
      }
      // ---- online softmax ----
#pragma unroll
      for (int qf = 0; qf < 2; ++qf) {
        float rm[4];
#pragma unroll
        for (int r = 0; r < 4; ++r)
          rm[r] = fmaxf(fmaxf(s[qf][0][r], s[qf][1][r]), fmaxf(s[qf][2][r], s[qf][3][r]));
#pragma unroll
        for (int r = 0; r < 4; ++r) {
          rm[r] = fmaxf(rm[r], __shfl_xor(rm[r], 1));
          rm[r] = fmaxf(rm[r], __shfl_xor(rm[r], 2));
          rm[r] = fmaxf(rm[r], __shfl_xor(rm[r], 4));
          rm[r] = fmaxf(rm[r], __shfl_xor(rm[r], 8));
        }
#pragma unroll
        for (int r = 0; r < 4; ++r) {
          float mn = fmaxf(mrun[qf][r], rm[r]);
          float al = __expf(mrun[qf][r] - mn);
          mrun[qf][r] = mn;
          float ps = 0.f;
#pragma unroll
          for (int nf = 0; nf < 4; ++nf) {
            float p = __expf(s[qf][nf][r] - mn);
            s[qf][nf][r] = p;
            ps += p;
          }
          lpart[qf][r] = lpart[qf][r] * al + ps;
#pragma unroll
          for (int df = 0; df < 4; ++df) o[qf][df][r] *= al;
        }
      }
      // ---- P (bf16) -> wave-private LDS slab, swizzled ----
      char* pb = (char*)lP[w];
#pragma unroll
      for (int qf = 0; qf < 2; ++qf)
#pragma unroll
        for (int nf = 0; nf < 4; ++nf)
#pragma unroll
          for (int r = 0; r < 4; ++r) {
            int rp = qf * 16 + hi * 4 + r;
            int col = nf * 16 + lr;
            int slot = (col >> 3) ^ (rp & 7);
            *reinterpret_cast<unsigned short*>(pb + rp * 128 + slot * 16 + (col & 7) * 2) =
                f2bf(s[qf][nf][r]);
          }
      asm volatile("s_waitcnt lgkmcnt(0)" ::: "memory");
      __builtin_amdgcn_sched_barrier(0);
      // ---- O += P V ----
      bf16x8 pfr[2][2];
#pragma unroll
      for (int qf = 0; qf < 2; ++qf)
#pragma unroll
        for (int kc = 0; kc < 2; ++kc) {
          int row = qf * 16 + lr;
          int slot = (kc * 4 + hi) ^ (row & 7);
          pfr[qf][kc] = *reinterpret_cast<const bf16x8*>(pb + row * 128 + slot * 16);
        }
#pragma unroll
      for (int qf = 0; qf < 2; ++qf)
#pragma unroll
        for (int df = 0; df < 4; ++df)
#pragma unroll
          for (int kc = 0; kc < 2; ++kc)
            o[qf][df] = __builtin_amdgcn_mfma_f32_16x16x32_bf16(pfr[qf][kc], vfr[df][kc], o[qf][df], 0, 0, 0);
    }
    // ---- end of iteration: full fence + barrier (drains prefetch vmcnt) ----
    __syncthreads();
  }

  // ---- finalize: full row-sum, normalize, store bf16 [b,t][h*64+d] ----
#pragma unroll
  for (int qf = 0; qf < 2; ++qf)
#pragma unroll
    for (int r = 0; r < 4; ++r) {
      float l = lpart[qf][r];
      l += __shfl_xor(l, 1);
      l += __shfl_xor(l, 2);
      l += __shfl_xor(l, 4);
      l += __shfl_xor(l, 8);
      float inv = 1.0f / l;
      int qrow = qbase + qf * 16 + hi * 4 + r;
#pragma unroll
      for (int df = 0; df < 4; ++df)
        Out[(size_t)(b * 1024 + qrow) * 1024 + h * 64 + df * 16 + lr] = f2bf(o[qf][df][r] * inv);
    }
}

// ---------------- LayerNorm over E=1024, wave per row -----------------------
__global__ __launch_bounds__(256) void lnorm(const unsigned short* __restrict__ X,
                                             unsigned short* __restrict__ Y,
                                             const float* __restrict__ gamma,
                                             const float* __restrict__ beta) {
  int rowi = (int)blockIdx.x * 4 + ((int)threadIdx.x >> 6);
  int lane = (int)threadIdx.x & 63;
  const unsigned short* row = X + (size_t)rowi * 1024;
  u16x8 v0 = reinterpret_cast<const u16x8*>(row)[lane];
  u16x8 v1 = reinterpret_cast<const u16x8*>(row)[lane + 64];
  float f0[8], f1[8];
  float s = 0.f, sq = 0.f;
#pragma unroll
  for (int j = 0; j < 8; ++j) {
    f0[j] = bf2f(v0[j]); f1[j] = bf2f(v1[j]);
    s  += f0[j] + f1[j];
    sq += f0[j] * f0[j] + f1[j] * f1[j];
  }
#pragma unroll
  for (int m = 1; m <= 32; m <<= 1) { s += __shfl_xor(s, m); sq += __shfl_xor(sq, m); }
  float mean = s * (1.0f / 1024.0f);
  float var  = sq * (1.0f / 1024.0f) - mean * mean;
  float rstd = rsqrtf(var + 1e-5f);
  int c0 = lane * 8, c1 = 512 + lane * 8;
  u16x8 o0, o1;
#pragma unroll
  for (int j = 0; j < 8; ++j) {
    o0[j] = f2bf((f0[j] - mean) * rstd * gamma[c0 + j] + beta[c0 + j]);
    o1[j] = f2bf((f1[j] - mean) * rstd * gamma[c1 + j] + beta[c1 + j]);
  }
  reinterpret_cast<u16x8*>(Y + (size_t)rowi * 1024)[lane]      = o0;
  reinterpret_cast<u16x8*>(Y + (size_t)rowi * 1024)[lane + 64] = o1;
}

// ---------------------------------------------------------------------------
extern "C" void kernel_launch(void* const* d_in, const int* in_sizes, int n_in,
                              void* d_out, int out_size, void* d_ws, size_t ws_size,
                              hipStream_t stream) {
  (void)in_sizes; (void)n_in; (void)out_size; (void)ws_size;
  const float* x     = (const float*)d_in[0];
  const float* Wq    = (const float*)d_in[1];
  const float* Wk    = (const float*)d_in[2];
  const float* Wv    = (const float*)d_in[3];
  const float* Wo    = (const float*)d_in[4];
  const float* gamma = (const float*)d_in[5];
  const float* beta  = (const float*)d_in[6];
  char* ws = (char*)d_ws;
  unsigned short* xb   = (unsigned short*)(ws);                    //  8MB [0,8)
  unsigned short* wcat = (unsigned short*)(ws + (8u  << 20));      //  6MB [8,14)
  unsigned short* wob  = (unsigned short*)(ws + (14u << 20));      //  2MB [14,16)
  unsigned short* qkv  = (unsigned short*)(ws + (16u << 20));      // 24MB [16,40)
  unsigned short* vht  = (unsigned short*)(ws + (40u << 20));      //  8MB [40,48)
  unsigned short* att  = (unsigned short*)(ws + (48u << 20));      //  8MB [48,56)
  unsigned short* lnb  = (unsigned short*)(ws + (56u << 20));      //  8MB [56,64)

  // fused converts (scale 1/sqrt(64)=0.125 folded into Wk)
  cvt_all<<<8192, 256, 0, stream>>>(x, Wq, Wk, Wv, Wo, xb, wcat, wob);
  // QKV projection: [4096,1024] x [3072,1024]^T -> bf16 [4096,3072]
  gemm_bt<0><<<768, 256, 0, stream>>>(xb, wcat, qkv, 4096, 3072, 1024);
  // V head-transpose repack
  vrepack<<<dim3(16, 16, 4), 256, 0, stream>>>(qkv, vht);
  // causal flash attention
  attn_fwd<<<512, 256, 0, stream>>>(qkv, vht, att);
  // LayerNorm
  lnorm<<<1024, 256, 0, stream>>>(att, lnb, gamma, beta);
  // output projection -> fp32 d_out
  gemm_bt<1><<<256, 256, 0, stream>>>(lnb, wob, (void*)d_out, 4096, 1024, 1024);
}